// Round 3
// baseline (1266.134 us; speedup 1.0000x reference)
//
#include <hip/hip_runtime.h>
#include <hip/hip_bf16.h>
#include <cmath>

#define D_MODEL 128
#define NUM_HEAD 4
#define HEAD_DIM 32
#define SEQ 4096
#define BATCH 2

__device__ __forceinline__ float tof(float x) { return x; }
__device__ __forceinline__ float tof(__hip_bfloat16 x) { return __bfloat162float(x); }
__device__ __forceinline__ void storef(float* p, size_t i, float v) { p[i] = v; }
__device__ __forceinline__ void storef(__hip_bfloat16* p, size_t i, float v) { p[i] = __float2bfloat16(v); }

// ---------------------------------------------------------------------------
// Kernel 0: dtype detector. Samples odd-index uint16s of w_q. If the buffer is
// f32, odd uint16s are low mantissa halves -> random bf16 bit patterns (~48%
// have absurd exponents). If genuinely bf16, all values are sane weights.
// flag = 1 -> float32 inputs, flag = 0 -> bf16 inputs.
// ---------------------------------------------------------------------------
__global__ void detect_kernel(const unsigned short* __restrict__ w, int* __restrict__ flag)
{
    const int t = threadIdx.x;   // 64 threads
    int weird = 0;
#pragma unroll
    for (int j = 0; j < 4; ++j) {
        const unsigned short v = w[(t * 4 + j) * 2 + 1];   // odd uint16 indices
        const float x = __uint_as_float((unsigned)v << 16);
        const float a = fabsf(x);
        if (a > 1e20f || (a > 0.f && a < 1e-20f)) weird++;
    }
#pragma unroll
    for (int off = 32; off; off >>= 1) weird += __shfl_xor(weird, off);
    if (t == 0) *flag = (weird < 32) ? 1 : 0;
}

// ---------------------------------------------------------------------------
// Kernel 1: x = embedding[seq] + PE;  Q/K/V = x @ W^T  (f32 to workspace)
// One block per token row, 128 threads = one output element each.
// ---------------------------------------------------------------------------
template <typename T>
__device__ __forceinline__ void qkv_body(
    const int* __restrict__ seq, const T* __restrict__ emb,
    const T* __restrict__ wq, const T* __restrict__ wk, const T* __restrict__ wv,
    float* __restrict__ Q, float* __restrict__ K, float* __restrict__ V)
{
    const int r = blockIdx.x;            // 0..B*S-1
    const int s = r & (SEQ - 1);
    const int e = threadIdx.x;           // 0..127
    __shared__ float xs[D_MODEL];

    const int tok = seq[r];
    const int i = e >> 1;
    const double denom = pow(10000.0, (double)i / 64.0);
    const double ang = (double)s / denom;
    const float pe = (float)((e & 1) ? cos(ang) : sin(ang));
    xs[e] = tof(emb[(size_t)tok * D_MODEL + e]) + pe;
    __syncthreads();

    const T* wqr = wq + e * D_MODEL;
    const T* wkr = wk + e * D_MODEL;
    const T* wvr = wv + e * D_MODEL;
    float aq = 0.f, ak = 0.f, av = 0.f;
#pragma unroll 8
    for (int d = 0; d < D_MODEL; ++d) {
        const float x = xs[d];
        aq += x * tof(wqr[d]);
        ak += x * tof(wkr[d]);
        av += x * tof(wvr[d]);
    }
    const size_t o = (size_t)r * D_MODEL + e;
    Q[o] = aq; K[o] = ak; V[o] = av;
}

__global__ __launch_bounds__(128) void qkv_kernel(
    const int* __restrict__ seq, const void* emb,
    const void* wq, const void* wk, const void* wv,
    float* __restrict__ Q, float* __restrict__ K, float* __restrict__ V,
    const int* __restrict__ flag)
{
    if (*flag)
        qkv_body<float>(seq, (const float*)emb, (const float*)wq,
                        (const float*)wk, (const float*)wv, Q, K, V);
    else
        qkv_body<__hip_bfloat16>(seq, (const __hip_bfloat16*)emb, (const __hip_bfloat16*)wq,
                                 (const __hip_bfloat16*)wk, (const __hip_bfloat16*)wv, Q, K, V);
}

// ---------------------------------------------------------------------------
// Kernel 2: flash attention per (b,h); "plain view" head split = flat slice
// base + h*S*32 viewed as [S,32]. score = abs(q.k)/sqrt(32) >= 0, causal mask
// in head-space. Inf-free online softmax (m starts at 0; masked p = 0; l >= 1
// provably). Block = 1024 threads = one 32x32 tile; thread (qi,kj) owns
// S[qi][kj] and O[qi][d=kj].
// ---------------------------------------------------------------------------
__global__ __launch_bounds__(1024) void attn_kernel(
    const float* __restrict__ Q, const float* __restrict__ K,
    const float* __restrict__ V, float* __restrict__ O)
{
    const int qt = blockIdx.x;
    const int bh = blockIdx.y;
    const int b = bh >> 2, h = bh & 3;
    const size_t base = (size_t)b * SEQ * D_MODEL + (size_t)h * SEQ * HEAD_DIM;
    const float* Qh = Q + base;
    const float* Kh = K + base;
    const float* Vh = V + base;
    float*       Oh = O + base;

    const int tid = threadIdx.x;
    const int kj = tid & 31;
    const int qi = tid >> 5;

    __shared__ __align__(16) float Qs[32][36];
    __shared__ __align__(16) float Ks[32][36];
    __shared__ float Vs[32][33];
    __shared__ float Ps[32][33];

    Qs[qi][kj] = Qh[(size_t)(qt * 32 + qi) * HEAD_DIM + kj];

    float m = 0.f, l = 0.f, o = 0.f;
    const float scale = 0.17677669529663687f;  // 1/sqrt(32)
    __syncthreads();

    for (int kt = 0; kt <= qt; ++kt) {
        Ks[qi][kj] = Kh[(size_t)(kt * 32 + qi) * HEAD_DIM + kj];
        Vs[qi][kj] = Vh[(size_t)(kt * 32 + qi) * HEAD_DIM + kj];
        __syncthreads();

        float sc = 0.f;
        const float4* qrow = (const float4*)&Qs[qi][0];
        const float4* krow = (const float4*)&Ks[kj][0];
#pragma unroll
        for (int j = 0; j < 8; ++j) {
            const float4 a = qrow[j], c = krow[j];
            sc += a.x * c.x + a.y * c.y + a.z * c.z + a.w * c.w;
        }
        sc = fabsf(sc) * scale;
        const bool masked = (kt == qt) && (kj > qi);

        float rm = masked ? 0.f : sc;
#pragma unroll
        for (int off = 16; off; off >>= 1) rm = fmaxf(rm, __shfl_xor(rm, off, 32));
        const float nm = fmaxf(m, rm);
        const float alpha = __expf(m - nm);
        const float p = masked ? 0.f : __expf(sc - nm);
        float rs = p;
#pragma unroll
        for (int off = 16; off; off >>= 1) rs += __shfl_xor(rs, off, 32);
        l = l * alpha + rs;
        o *= alpha;
        m = nm;

        Ps[qi][kj] = p;
        __syncthreads();

#pragma unroll 8
        for (int j = 0; j < 32; ++j) o += Ps[qi][j] * Vs[j][kj];
        __syncthreads();
    }

    Oh[(size_t)(qt * 32 + qi) * HEAD_DIM + kj] = o / l;
}

// ---------------------------------------------------------------------------
// Kernel 3: out = att @ Wo^T
// ---------------------------------------------------------------------------
template <typename T>
__device__ __forceinline__ void out_proj_body(
    const float* __restrict__ att, const T* __restrict__ wo, T* __restrict__ out)
{
    const int r = blockIdx.x;
    const int e = threadIdx.x;
    __shared__ float xs[D_MODEL];
    xs[e] = att[(size_t)r * D_MODEL + e];
    __syncthreads();

    const T* wr = wo + e * D_MODEL;
    float acc = 0.f;
#pragma unroll 8
    for (int d = 0; d < D_MODEL; ++d) acc += xs[d] * tof(wr[d]);
    storef(out, (size_t)r * D_MODEL + e, acc);
}

__global__ __launch_bounds__(128) void out_proj_kernel(
    const float* __restrict__ att, const void* wo, void* out,
    const int* __restrict__ flag)
{
    if (*flag)
        out_proj_body<float>(att, (const float*)wo, (float*)out);
    else
        out_proj_body<__hip_bfloat16>(att, (const __hip_bfloat16*)wo, (__hip_bfloat16*)out);
}

extern "C" void kernel_launch(void* const* d_in, const int* in_sizes, int n_in,
                              void* d_out, int out_size, void* d_ws, size_t ws_size,
                              hipStream_t stream) {
    const int* seq = (const int*)d_in[0];
    const void* emb = d_in[1];
    const void* wq  = d_in[2];
    const void* wk  = d_in[3];
    const void* wv  = d_in[4];
    const void* wo  = d_in[5];

    const size_t N = (size_t)BATCH * SEQ * D_MODEL;   // 1,048,576
    int*   flag = (int*)d_ws;
    float* Q = (float*)((char*)d_ws + 256);
    float* K = Q + N;
    float* V = K + N;
    float* A = Q;   // alias: each attn block reads only its own Q rows first

    detect_kernel<<<dim3(1), dim3(64), 0, stream>>>((const unsigned short*)wq, flag);
    qkv_kernel<<<dim3(BATCH * SEQ), dim3(128), 0, stream>>>(seq, emb, wq, wk, wv, Q, K, V, flag);
    attn_kernel<<<dim3(SEQ / 32, BATCH * NUM_HEAD), dim3(1024), 0, stream>>>(Q, K, V, A);
    out_proj_kernel<<<dim3(BATCH * SEQ), dim3(128), 0, stream>>>(A, wo, d_out, flag);
}

// Round 5
// 836.624 us; speedup vs baseline: 1.5134x; 1.5134x over previous
//
#include <hip/hip_runtime.h>
#include <hip/hip_bf16.h>
#include <cmath>

#define D_MODEL 128
#define NUM_HEAD 4
#define HEAD_DIM 32
#define SEQ 4096
#define BATCH 2
#define QT 64      // q-rows per attention block (= lanes per wave)
#define NW 16      // waves per attention block (k-split factor)
#define CHUNK 16   // k's per softmax-rescale chunk
#define RROWS 16   // token rows per projection block

__device__ __forceinline__ float tof(float x) { return x; }
__device__ __forceinline__ float tof(__hip_bfloat16 x) { return __bfloat162float(x); }
__device__ __forceinline__ void storef(float* p, size_t i, float v) { p[i] = v; }
__device__ __forceinline__ void storef(__hip_bfloat16* p, size_t i, float v) { p[i] = __float2bfloat16(v); }

// ---------------------------------------------------------------------------
// Kernel 0: dtype detector (f32 vs bf16 inputs), as in R3 (passed).
// ---------------------------------------------------------------------------
__global__ void detect_kernel(const unsigned short* __restrict__ w, int* __restrict__ flag)
{
    const int t = threadIdx.x;   // 64 threads
    int weird = 0;
#pragma unroll
    for (int j = 0; j < 4; ++j) {
        const unsigned short v = w[(t * 4 + j) * 2 + 1];
        const float x = __uint_as_float((unsigned)v << 16);
        const float a = fabsf(x);
        if (a > 1e20f || (a > 0.f && a < 1e-20f)) weird++;
    }
#pragma unroll
    for (int off = 32; off; off >>= 1) weird += __shfl_xor(weird, off);
    if (t == 0) *flag = (weird < 32) ? 1 : 0;
}

// ---------------------------------------------------------------------------
// Kernel 1: x = embedding[seq] + PE;  Q/K/V = x @ W^T  (f32 to workspace)
// Block = 128 threads (one per output dim), handles RROWS=16 token rows:
// weight rows are loaded once per 16 rows (16x reuse), x broadcast from LDS.
// ---------------------------------------------------------------------------
template <typename T>
__device__ __forceinline__ void qkv_body(
    const int* __restrict__ seq, const T* __restrict__ emb,
    const T* __restrict__ wq, const T* __restrict__ wk, const T* __restrict__ wv,
    float* __restrict__ Q, float* __restrict__ K, float* __restrict__ V)
{
    const int e = threadIdx.x;               // 0..127 output dim
    const int r0 = blockIdx.x * RROWS;
    __shared__ __align__(16) float xs[RROWS][D_MODEL];

    const int i = e >> 1;
    const double denom = pow(10000.0, (double)i / 64.0);
#pragma unroll
    for (int r = 0; r < RROWS; ++r) {
        const int row = r0 + r;
        const int s = row & (SEQ - 1);
        const double ang = (double)s / denom;
        const float pe = (float)((e & 1) ? cos(ang) : sin(ang));
        xs[r][e] = tof(emb[(size_t)seq[row] * D_MODEL + e]) + pe;
    }
    __syncthreads();

    const T* wqr = wq + e * D_MODEL;
    const T* wkr = wk + e * D_MODEL;
    const T* wvr = wv + e * D_MODEL;
    float aq[RROWS], ak[RROWS], av[RROWS];
#pragma unroll
    for (int r = 0; r < RROWS; ++r) { aq[r] = 0.f; ak[r] = 0.f; av[r] = 0.f; }

#pragma unroll
    for (int c = 0; c < 32; ++c) {
        const float q0 = tof(wqr[4*c]), q1 = tof(wqr[4*c+1]), q2 = tof(wqr[4*c+2]), q3 = tof(wqr[4*c+3]);
        const float k0 = tof(wkr[4*c]), k1 = tof(wkr[4*c+1]), k2 = tof(wkr[4*c+2]), k3 = tof(wkr[4*c+3]);
        const float v0 = tof(wvr[4*c]), v1 = tof(wvr[4*c+1]), v2 = tof(wvr[4*c+2]), v3 = tof(wvr[4*c+3]);
#pragma unroll
        for (int r = 0; r < RROWS; ++r) {
            const float4 x4 = *(const float4*)&xs[r][4*c];   // wave-uniform -> broadcast
            aq[r] += x4.x*q0 + x4.y*q1 + x4.z*q2 + x4.w*q3;
            ak[r] += x4.x*k0 + x4.y*k1 + x4.z*k2 + x4.w*k3;
            av[r] += x4.x*v0 + x4.y*v1 + x4.z*v2 + x4.w*v3;
        }
    }
#pragma unroll
    for (int r = 0; r < RROWS; ++r) {
        const size_t o = (size_t)(r0 + r) * D_MODEL + e;
        Q[o] = aq[r]; K[o] = ak[r]; V[o] = av[r];
    }
}

__global__ __launch_bounds__(128) void qkv_kernel(
    const int* __restrict__ seq, const void* emb,
    const void* wq, const void* wk, const void* wv,
    float* __restrict__ Q, float* __restrict__ K, float* __restrict__ V,
    const int* __restrict__ flag)
{
    if (*flag)
        qkv_body<float>(seq, (const float*)emb, (const float*)wq,
                        (const float*)wk, (const float*)wv, Q, K, V);
    else
        qkv_body<__hip_bfloat16>(seq, (const __hip_bfloat16*)emb, (const __hip_bfloat16*)wq,
                                 (const __hip_bfloat16*)wk, (const __hip_bfloat16*)wv, Q, K, V);
}

// ---------------------------------------------------------------------------
// Kernel 2: attention. Thread = one q-row: q[32], o[32], (m,l) in registers;
// no shuffles/barriers in the K-loop. All lanes of a wave share k, so K/V row
// reads are wave-uniform -> s_load + v_fmac(v,s,v). The block's 16 waves each
// take 1/16 of the k-range; partials merged via a 4-pass 41KB LDS combine.
// Inf-free softmax: scores = |qk|/sqrt(32) >= 0, m starts 0, masked p = 0.
// ---------------------------------------------------------------------------
__global__ __launch_bounds__(1024, 4) void attn_kernel(
    const float* __restrict__ Q, const float* __restrict__ K,
    const float* __restrict__ V, float* __restrict__ O)
{
    const int bx = blockIdx.x;
    const int qt = (bx & 1) ? (63 - (bx >> 1)) : (bx >> 1);  // big/small interleave
    const int bh = blockIdx.y;
    const size_t base = (size_t)(bh >> 2) * SEQ * D_MODEL + (size_t)(bh & 3) * SEQ * HEAD_DIM;
    const float* Qh = Q + base;
    const float* Kh = K + base;
    const float* Vh = V + base;
    float*       Oh = O + base;

    const int tid  = threadIdx.x;
    const int wid  = __builtin_amdgcn_readfirstlane(tid >> 6);  // wave-uniform!
    const int lane = tid & 63;
    const int qrow = qt * QT + lane;

    float qv[32];
    {
        const float4* qp = (const float4*)(Qh + (size_t)qrow * HEAD_DIM);
#pragma unroll
        for (int j4 = 0; j4 < 8; ++j4) {
            const float4 t = qp[j4];
            qv[4*j4] = t.x; qv[4*j4+1] = t.y; qv[4*j4+2] = t.z; qv[4*j4+3] = t.w;
        }
    }

    float ov[32];
#pragma unroll
    for (int j = 0; j < 32; ++j) ov[j] = 0.f;
    float m = 0.f, l = 0.f;
    const float scale = 0.17677669529663687f;   // 1/sqrt(32)

    const int totalK = (qt + 1) * QT;           // causal bound for this q-tile
    const int share  = totalK >> 4;             // per-wave k-range, multiple of 4
    const int kbeg   = wid * share;
    const int kend   = kbeg + share;

    for (int k0 = kbeg; k0 < kend; k0 += CHUNK) {
        float p[CHUNK];
        float cm = 0.f;
#pragma unroll
        for (int i = 0; i < CHUNK; ++i) {
            const int k  = k0 + i;
            const int ka = (k < kend) ? k : (kend - 1);        // uniform clamp
            const float* kr = Kh + (size_t)ka * HEAD_DIM;      // s_load path
            float sc = 0.f;
#pragma unroll
            for (int j = 0; j < 32; ++j) sc += qv[j] * kr[j];
            sc = fabsf(sc) * scale;
            sc = (k < kend && k <= qrow) ? sc : -1.f;          // -1 sentinel
            p[i] = sc;
            cm = fmaxf(cm, sc);
        }
        const float nm = fmaxf(m, cm);
        if (nm > m) {                                          // rare rescale
            const float alpha = __expf(m - nm);
            l *= alpha;
#pragma unroll
            for (int j = 0; j < 32; ++j) ov[j] *= alpha;
            m = nm;
        }
#pragma unroll
        for (int i = 0; i < CHUNK; ++i) {
            const int k  = k0 + i;
            const int ka = (k < kend) ? k : (kend - 1);
            const float* vr = Vh + (size_t)ka * HEAD_DIM;      // s_load path
            const float pe_ = (p[i] >= 0.f) ? __expf(p[i] - m) : 0.f;
            l += pe_;
#pragma unroll
            for (int j = 0; j < 32; ++j) ov[j] += pe_ * vr[j];
        }
    }

    // combine the 16 per-wave partials; 4 passes of 8 dims keep LDS at 41KB
    __shared__ float part[NW][QT][10];
#pragma unroll
    for (int pass = 0; pass < 4; ++pass) {
        __syncthreads();
#pragma unroll
        for (int j = 0; j < 8; ++j) part[wid][lane][j] = ov[pass * 8 + j];
        part[wid][lane][8] = m;
        part[wid][lane][9] = l;
        __syncthreads();
        if (tid < 512) {
            const int r = tid >> 3;        // 0..63
            const int j = tid & 7;
            float M = 0.f;
#pragma unroll
            for (int w = 0; w < NW; ++w) M = fmaxf(M, part[w][r][8]);
            float lsum = 0.f, osum = 0.f;
#pragma unroll
            for (int w = 0; w < NW; ++w) {
                const float a = __expf(part[w][r][8] - M);
                lsum += a * part[w][r][9];
                osum += a * part[w][r][j];
            }
            Oh[(size_t)(qt * QT + r) * HEAD_DIM + pass * 8 + j] = osum / lsum;
        }
    }
}

// ---------------------------------------------------------------------------
// Kernel 3: out = att @ Wo^T  (16-row weight reuse, same pattern as qkv)
// ---------------------------------------------------------------------------
template <typename T>
__device__ __forceinline__ void out_proj_body(
    const float* __restrict__ att, const T* __restrict__ wo, T* __restrict__ out)
{
    const int e = threadIdx.x;
    const int r0 = blockIdx.x * RROWS;
    __shared__ __align__(16) float xs[RROWS][D_MODEL];
#pragma unroll
    for (int r = 0; r < RROWS; ++r)
        xs[r][e] = att[(size_t)(r0 + r) * D_MODEL + e];
    __syncthreads();

    const T* wr = wo + e * D_MODEL;
    float acc[RROWS];
#pragma unroll
    for (int r = 0; r < RROWS; ++r) acc[r] = 0.f;
#pragma unroll
    for (int c = 0; c < 32; ++c) {
        const float w0 = tof(wr[4*c]), w1 = tof(wr[4*c+1]), w2 = tof(wr[4*c+2]), w3 = tof(wr[4*c+3]);
#pragma unroll
        for (int r = 0; r < RROWS; ++r) {
            const float4 x4 = *(const float4*)&xs[r][4*c];
            acc[r] += x4.x*w0 + x4.y*w1 + x4.z*w2 + x4.w*w3;
        }
    }
#pragma unroll
    for (int r = 0; r < RROWS; ++r)
        storef(out, (size_t)(r0 + r) * D_MODEL + e, acc[r]);
}

__global__ __launch_bounds__(128) void out_proj_kernel(
    const float* __restrict__ att, const void* wo, void* out,
    const int* __restrict__ flag)
{
    if (*flag)
        out_proj_body<float>(att, (const float*)wo, (float*)out);
    else
        out_proj_body<__hip_bfloat16>(att, (const __hip_bfloat16*)wo, (__hip_bfloat16*)out);
}

extern "C" void kernel_launch(void* const* d_in, const int* in_sizes, int n_in,
                              void* d_out, int out_size, void* d_ws, size_t ws_size,
                              hipStream_t stream) {
    const int* seq = (const int*)d_in[0];
    const void* emb = d_in[1];
    const void* wq  = d_in[2];
    const void* wk  = d_in[3];
    const void* wv  = d_in[4];
    const void* wo  = d_in[5];

    const size_t N = (size_t)BATCH * SEQ * D_MODEL;   // 1,048,576
    int*   flag = (int*)d_ws;
    float* Q = (float*)((char*)d_ws + 256);
    float* K = Q + N;
    float* V = K + N;
    float* A = Q;   // alias: each attn block reads only its own Q rows first

    detect_kernel<<<dim3(1), dim3(64), 0, stream>>>((const unsigned short*)wq, flag);
    qkv_kernel<<<dim3(BATCH * SEQ / RROWS), dim3(128), 0, stream>>>(seq, emb, wq, wk, wv, Q, K, V, flag);
    attn_kernel<<<dim3(SEQ / QT, BATCH * NUM_HEAD), dim3(NW * 64), 0, stream>>>(Q, K, V, A);
    out_proj_kernel<<<dim3(BATCH * SEQ / RROWS), dim3(128), 0, stream>>>(A, wo, d_out, flag);
}

// Round 6
// 814.636 us; speedup vs baseline: 1.5542x; 1.0270x over previous
//
#include <hip/hip_runtime.h>
#include <hip/hip_bf16.h>
#include <cmath>

#define D_MODEL 128
#define NUM_HEAD 4
#define HEAD_DIM 32
#define SEQ 4096
#define BATCH 2
#define QT 64      // q-rows per attention block (= lanes per wave)
#define NW 8       // waves per attention block (k-split factor)
#define CHUNK 16   // k's per softmax-rescale chunk
#define RROWS 16   // token rows per projection block

__device__ __forceinline__ float tof(float x) { return x; }
__device__ __forceinline__ float tof(__hip_bfloat16 x) { return __bfloat162float(x); }
__device__ __forceinline__ void storef(float* p, size_t i, float v) { p[i] = v; }
__device__ __forceinline__ void storef(__hip_bfloat16* p, size_t i, float v) { p[i] = __float2bfloat16(v); }

// ---------------------------------------------------------------------------
// Kernel 0: dtype detector (f32 vs bf16 inputs), unchanged (R3/R5 passed).
// ---------------------------------------------------------------------------
__global__ void detect_kernel(const unsigned short* __restrict__ w, int* __restrict__ flag)
{
    const int t = threadIdx.x;   // 64 threads
    int weird = 0;
#pragma unroll
    for (int j = 0; j < 4; ++j) {
        const unsigned short v = w[(t * 4 + j) * 2 + 1];
        const float x = __uint_as_float((unsigned)v << 16);
        const float a = fabsf(x);
        if (a > 1e20f || (a > 0.f && a < 1e-20f)) weird++;
    }
#pragma unroll
    for (int off = 32; off; off >>= 1) weird += __shfl_xor(weird, off);
    if (t == 0) *flag = (weird < 32) ? 1 : 0;
}

// ---------------------------------------------------------------------------
// Kernel 1: x = embedding[seq] + PE;  Q/K/V = x @ W^T  (f32 to workspace)
// ---------------------------------------------------------------------------
template <typename T>
__device__ __forceinline__ void qkv_body(
    const int* __restrict__ seq, const T* __restrict__ emb,
    const T* __restrict__ wq, const T* __restrict__ wk, const T* __restrict__ wv,
    float* __restrict__ Q, float* __restrict__ K, float* __restrict__ V)
{
    const int e = threadIdx.x;               // 0..127 output dim
    const int r0 = blockIdx.x * RROWS;
    __shared__ __align__(16) float xs[RROWS][D_MODEL];

    const int i = e >> 1;
    const double denom = pow(10000.0, (double)i / 64.0);
#pragma unroll
    for (int r = 0; r < RROWS; ++r) {
        const int row = r0 + r;
        const int s = row & (SEQ - 1);
        const double ang = (double)s / denom;
        const float pe = (float)((e & 1) ? cos(ang) : sin(ang));
        xs[r][e] = tof(emb[(size_t)seq[row] * D_MODEL + e]) + pe;
    }
    __syncthreads();

    const T* wqr = wq + e * D_MODEL;
    const T* wkr = wk + e * D_MODEL;
    const T* wvr = wv + e * D_MODEL;
    float aq[RROWS], ak[RROWS], av[RROWS];
#pragma unroll
    for (int r = 0; r < RROWS; ++r) { aq[r] = 0.f; ak[r] = 0.f; av[r] = 0.f; }

#pragma unroll
    for (int c = 0; c < 32; ++c) {
        const float q0 = tof(wqr[4*c]), q1 = tof(wqr[4*c+1]), q2 = tof(wqr[4*c+2]), q3 = tof(wqr[4*c+3]);
        const float k0 = tof(wkr[4*c]), k1 = tof(wkr[4*c+1]), k2 = tof(wkr[4*c+2]), k3 = tof(wkr[4*c+3]);
        const float v0 = tof(wvr[4*c]), v1 = tof(wvr[4*c+1]), v2 = tof(wvr[4*c+2]), v3 = tof(wvr[4*c+3]);
#pragma unroll
        for (int r = 0; r < RROWS; ++r) {
            const float4 x4 = *(const float4*)&xs[r][4*c];   // wave-uniform -> broadcast
            aq[r] += x4.x*q0 + x4.y*q1 + x4.z*q2 + x4.w*q3;
            ak[r] += x4.x*k0 + x4.y*k1 + x4.z*k2 + x4.w*k3;
            av[r] += x4.x*v0 + x4.y*v1 + x4.z*v2 + x4.w*v3;
        }
    }
#pragma unroll
    for (int r = 0; r < RROWS; ++r) {
        const size_t o = (size_t)(r0 + r) * D_MODEL + e;
        Q[o] = aq[r]; K[o] = ak[r]; V[o] = av[r];
    }
}

__global__ __launch_bounds__(128) void qkv_kernel(
    const int* __restrict__ seq, const void* emb,
    const void* wq, const void* wk, const void* wv,
    float* __restrict__ Q, float* __restrict__ K, float* __restrict__ V,
    const int* __restrict__ flag)
{
    if (*flag)
        qkv_body<float>(seq, (const float*)emb, (const float*)wq,
                        (const float*)wk, (const float*)wv, Q, K, V);
    else
        qkv_body<__hip_bfloat16>(seq, (const __hip_bfloat16*)emb, (const __hip_bfloat16*)wq,
                                 (const __hip_bfloat16*)wk, (const __hip_bfloat16*)wv, Q, K, V);
}

// ---------------------------------------------------------------------------
// Kernel 2: attention. Thread = one q-row (q[32], o[32], m, l in VGPRs);
// no shuffles/barriers in the K-loop; wave-uniform K/V row addresses ->
// s_load broadcast (R5: SGPR_Count=112 confirms). Block = 512 thr = 8 waves,
// each takes 1/8 of the causal k-range; partials merged via 20KB LDS combine.
// launch_bounds(512,2): 256-VGPR budget so the ~100 live VGPRs do NOT spill
// (R5's (1024,4) capped at 64 VGPR -> 860MB/disp scratch traffic).
// ---------------------------------------------------------------------------
__global__ __launch_bounds__(512, 2) void attn_kernel(
    const float* __restrict__ Q, const float* __restrict__ K,
    const float* __restrict__ V, float* __restrict__ O)
{
    const int bx = blockIdx.x;
    const int qt = (bx & 1) ? (63 - (bx >> 1)) : (bx >> 1);  // big/small interleave
    const int bh = blockIdx.y;
    const size_t base = (size_t)(bh >> 2) * SEQ * D_MODEL + (size_t)(bh & 3) * SEQ * HEAD_DIM;
    const float* Qh = Q + base;
    const float* Kh = K + base;
    const float* Vh = V + base;
    float*       Oh = O + base;

    const int tid  = threadIdx.x;
    const int wid  = __builtin_amdgcn_readfirstlane(tid >> 6);  // wave-uniform
    const int lane = tid & 63;
    const int qrow = qt * QT + lane;

    float qv[32];
    {
        const float4* qp = (const float4*)(Qh + (size_t)qrow * HEAD_DIM);
#pragma unroll
        for (int j4 = 0; j4 < 8; ++j4) {
            const float4 t = qp[j4];
            qv[4*j4] = t.x; qv[4*j4+1] = t.y; qv[4*j4+2] = t.z; qv[4*j4+3] = t.w;
        }
    }

    float ov[32];
#pragma unroll
    for (int j = 0; j < 32; ++j) ov[j] = 0.f;
    float m = 0.f, l = 0.f;
    const float scale = 0.17677669529663687f;   // 1/sqrt(32)

    const int totalK = (qt + 1) * QT;           // causal bound for this q-tile
    const int share  = totalK >> 3;             // per-wave k-range (multiple of 8)
    const int kbeg   = wid * share;
    const int kend   = kbeg + share;

    for (int k0 = kbeg; k0 < kend; k0 += CHUNK) {
        float p[CHUNK];
        float cm = 0.f;
#pragma unroll
        for (int i = 0; i < CHUNK; ++i) {
            const int k  = k0 + i;
            const int ka = (k < kend) ? k : (kend - 1);        // uniform clamp
            const float* kr = Kh + (size_t)ka * HEAD_DIM;      // s_load path
            float sc = 0.f;
#pragma unroll
            for (int j = 0; j < 32; ++j) sc += qv[j] * kr[j];
            sc = fabsf(sc) * scale;
            sc = (k < kend && k <= qrow) ? sc : -1.f;          // -1 sentinel
            p[i] = sc;
            cm = fmaxf(cm, sc);
        }
        const float nm = fmaxf(m, cm);
        if (nm > m) {                                          // occasional rescale
            const float alpha = __expf(m - nm);
            l *= alpha;
#pragma unroll
            for (int j = 0; j < 32; ++j) ov[j] *= alpha;
            m = nm;
        }
#pragma unroll
        for (int i = 0; i < CHUNK; ++i) {
            const int k  = k0 + i;
            const int ka = (k < kend) ? k : (kend - 1);
            const float* vr = Vh + (size_t)ka * HEAD_DIM;      // s_load path
            const float pe_ = (p[i] >= 0.f) ? __expf(p[i] - m) : 0.f;
            l += pe_;
#pragma unroll
            for (int j = 0; j < 32; ++j) ov[j] += pe_ * vr[j];
        }
    }

    // combine the 8 per-wave partials; 4 passes of 8 dims, LDS = 20.5KB
    __shared__ float part[NW][QT][10];
#pragma unroll
    for (int pass = 0; pass < 4; ++pass) {
        __syncthreads();
#pragma unroll
        for (int j = 0; j < 8; ++j) part[wid][lane][j] = ov[pass * 8 + j];
        part[wid][lane][8] = m;
        part[wid][lane][9] = l;
        __syncthreads();
        {
            const int r = tid >> 3;        // 0..63
            const int j = tid & 7;
            float M = 0.f;
#pragma unroll
            for (int w = 0; w < NW; ++w) M = fmaxf(M, part[w][r][8]);
            float lsum = 0.f, osum = 0.f;
#pragma unroll
            for (int w = 0; w < NW; ++w) {
                const float a = __expf(part[w][r][8] - M);
                lsum += a * part[w][r][9];
                osum += a * part[w][r][j];
            }
            Oh[(size_t)(qt * QT + r) * HEAD_DIM + pass * 8 + j] = osum / lsum;
        }
    }
}

// ---------------------------------------------------------------------------
// Kernel 3: out = att @ Wo^T  (16-row weight reuse)
// ---------------------------------------------------------------------------
template <typename T>
__device__ __forceinline__ void out_proj_body(
    const float* __restrict__ att, const T* __restrict__ wo, T* __restrict__ out)
{
    const int e = threadIdx.x;
    const int r0 = blockIdx.x * RROWS;
    __shared__ __align__(16) float xs[RROWS][D_MODEL];
#pragma unroll
    for (int r = 0; r < RROWS; ++r)
        xs[r][e] = att[(size_t)(r0 + r) * D_MODEL + e];
    __syncthreads();

    const T* wr = wo + e * D_MODEL;
    float acc[RROWS];
#pragma unroll
    for (int r = 0; r < RROWS; ++r) acc[r] = 0.f;
#pragma unroll
    for (int c = 0; c < 32; ++c) {
        const float w0 = tof(wr[4*c]), w1 = tof(wr[4*c+1]), w2 = tof(wr[4*c+2]), w3 = tof(wr[4*c+3]);
#pragma unroll
        for (int r = 0; r < RROWS; ++r) {
            const float4 x4 = *(const float4*)&xs[r][4*c];
            acc[r] += x4.x*w0 + x4.y*w1 + x4.z*w2 + x4.w*w3;
        }
    }
#pragma unroll
    for (int r = 0; r < RROWS; ++r)
        storef(out, (size_t)(r0 + r) * D_MODEL + e, acc[r]);
}

__global__ __launch_bounds__(128) void out_proj_kernel(
    const float* __restrict__ att, const void* wo, void* out,
    const int* __restrict__ flag)
{
    if (*flag)
        out_proj_body<float>(att, (const float*)wo, (float*)out);
    else
        out_proj_body<__hip_bfloat16>(att, (const __hip_bfloat16*)wo, (__hip_bfloat16*)out);
}

extern "C" void kernel_launch(void* const* d_in, const int* in_sizes, int n_in,
                              void* d_out, int out_size, void* d_ws, size_t ws_size,
                              hipStream_t stream) {
    const int* seq = (const int*)d_in[0];
    const void* emb = d_in[1];
    const void* wq  = d_in[2];
    const void* wk  = d_in[3];
    const void* wv  = d_in[4];
    const void* wo  = d_in[5];

    const size_t N = (size_t)BATCH * SEQ * D_MODEL;   // 1,048,576
    int*   flag = (int*)d_ws;
    float* Q = (float*)((char*)d_ws + 256);
    float* K = Q + N;
    float* V = K + N;
    float* A = Q;   // alias: each attn block reads only its own Q rows first

    detect_kernel<<<dim3(1), dim3(64), 0, stream>>>((const unsigned short*)wq, flag);
    qkv_kernel<<<dim3(BATCH * SEQ / RROWS), dim3(128), 0, stream>>>(seq, emb, wq, wk, wv, Q, K, V, flag);
    attn_kernel<<<dim3(SEQ / QT, BATCH * NUM_HEAD), dim3(NW * 64), 0, stream>>>(Q, K, V, A);
    out_proj_kernel<<<dim3(BATCH * SEQ / RROWS), dim3(128), 0, stream>>>(A, wo, d_out, flag);
}